// Round 3
// baseline (274.330 us; speedup 1.0000x reference)
//
#include <hip/hip_runtime.h>
#include <hip/hip_bf16.h>

// ---- problem constants ----
#define L_IN   220500
#define PADK   1024
#define LP     222548            // L_IN + 2048 (reflect-padded length)
#define LPP    222560            // LP rounded up to 16B-aligned rows
#define BATCH  32
#define HOPSZ  512
#define T_FR   431               // frames per batch
#define F_BINS 1025
#define M_TOT  (BATCH * T_FR)    // 13792 frames
#define N_GEMM 2048              // interleaved rows n' = 2k + c for k = 0..1023
#define K_TOT  2048
#define NT_K   64                // K tiles of 32
#define GEMM_BLOCKS 864          // 108 m-tiles (BM=128) x 8 n-tiles (BN=256)
#define NYQ_BLOCKS  48
#define XBLOCKS 3488             // 109 per batch x 32
#define WBLOCKS 2048

typedef short short8 __attribute__((ext_vector_type(8)));
typedef float floatx4 __attribute__((ext_vector_type(4)));

__device__ __forceinline__ void glds16(const void* g, void* l) {
    __builtin_amdgcn_global_load_lds(
        (const __attribute__((address_space(1))) void*)g,
        (__attribute__((address_space(3))) void*)l, 16, 0, 0);
}

__device__ __forceinline__ short f2bf(float f) {
    __hip_bfloat16 h = __float2bfloat16(f);
    return *reinterpret_cast<short*>(&h);
}

// ---- pass 1: fused reflect-pad x->bf16 (blocks 0..3487) + weight interleave (3488..5535)
__global__ void k_prep(const float* __restrict__ x,
                       const float* __restrict__ wcos, const float* __restrict__ wsin,
                       __hip_bfloat16* __restrict__ xp, __hip_bfloat16* __restrict__ wb) {
    int blk = blockIdx.x;
    if (blk < XBLOCKS) {
        int b = blk / 109, ix = blk - b * 109;
        int i0 = (ix * 256 + threadIdx.x) * 8;
        if (i0 >= LP) return;
        const float* xb = x + (size_t)b * L_IN;
        __hip_bfloat16* xpb = xp + (size_t)b * LPP;
        if (i0 >= PADK && i0 + 8 <= PADK + L_IN) {
            const float4* s4 = (const float4*)(xb + (i0 - PADK));
            float4 a = s4[0], d = s4[1];
            short8 o;
            o[0]=f2bf(a.x); o[1]=f2bf(a.y); o[2]=f2bf(a.z); o[3]=f2bf(a.w);
            o[4]=f2bf(d.x); o[5]=f2bf(d.y); o[6]=f2bf(d.z); o[7]=f2bf(d.w);
            *(short8*)((short*)xpb + i0) = o;
        } else {
            for (int u = 0; u < 8; ++u) {
                int i = i0 + u;
                if (i >= LP) break;
                int j = i - PADK;
                if (j < 0) j = -j;
                if (j >= L_IN) j = 2 * L_IN - 2 - j;
                xpb[i] = __float2bfloat16(xb[j]);
            }
        }
    } else {
        int i0 = ((blk - XBLOCKS) * 256 + threadIdx.x) * 8;   // < 2048*2048 exactly
        int np = i0 >> 11;
        int k  = i0 & (K_TOT - 1);
        int kf = np >> 1;
        const float* src = ((np & 1) ? wsin : wcos) + (size_t)kf * K_TOT + k;
        float4 a = ((const float4*)src)[0], d = ((const float4*)src)[1];
        short8 o;
        o[0]=f2bf(a.x); o[1]=f2bf(a.y); o[2]=f2bf(a.z); o[3]=f2bf(a.w);
        o[4]=f2bf(d.x); o[5]=f2bf(d.y); o[6]=f2bf(d.z); o[7]=f2bf(d.w);
        *(short8*)((short*)wb + i0) = o;
    }
}

// ---- pass 2: 128x256 (BM x BN) bf16 MFMA GEMM (C^T), BK=32, triple-buffered LDS,
// 1 barrier/tile, counted vmcnt(3), 2 blocks/CU (4 waves/SIMD) so cross-block TLP
// hides lgkm/barrier stalls. Nyquist bin k=1024 via tail blocks (>= 864).
//
// LDS 72 KiB: A[3][128][32] shorts at 0 (3x4096), B[3][256][32] at 12288 (3x8192).
// Swizzle (rows are 64B = 4 x 16B chunks): LDS[row][c] = global[row][c ^ (row&3)].
// ds_read_b128 quad pattern (chunk = quad ^ (l15&3)) -> exactly 8 accesses/bank
// = the b128 floor -> conflict-free. Staging pre-swizzles the global source chunk.
#define BARRIER { asm volatile("" ::: "memory"); __builtin_amdgcn_s_barrier(); asm volatile("" ::: "memory"); }
#define VMW(N)  asm volatile("s_waitcnt vmcnt(" #N ")" ::: "memory")
#define SCHED0  __builtin_amdgcn_sched_barrier(0)
#define SP1     __builtin_amdgcn_s_setprio(1)
#define SP0     __builtin_amdgcn_s_setprio(0)

__global__ __launch_bounds__(512, 4) void k_gemm(
    const __hip_bfloat16* __restrict__ xp,
    const __hip_bfloat16* __restrict__ wb,
    const float* __restrict__ wcos,
    float* __restrict__ out) {

    __shared__ short lds[36864];   // 72 KiB

    const int tid  = threadIdx.x;
    const int wave = tid >> 6;
    const int lane = tid & 63;

    // ---- Nyquist tail blocks: k=1024 row (wsin==0 -> imag==0) ----
    if (blockIdx.x >= GEMM_BLOCKS) {
        const int gw = (blockIdx.x - GEMM_BLOCKS) * 8 + wave;   // 0..383
        const float* wr = wcos + (size_t)1024 * K_TOT;
        for (int f = gw; f < M_TOT; f += NYQ_BLOCKS * 8) {
            int b = f / T_FR, t = f - b * T_FR;
            const __hip_bfloat16* xr = xp + (size_t)b * LPP + t * HOPSZ;
            float sum = 0.f;
            #pragma unroll
            for (int i = 0; i < 4; ++i) {
                int s = i * 512 + lane * 8;
                short8 xv = *(const short8*)((const short*)xr + s);
                const float4* wv = (const float4*)(wr + s);
                float4 w0 = wv[0], w1 = wv[1];
                float xs[8];
                #pragma unroll
                for (int u = 0; u < 8; ++u)
                    xs[u] = __uint_as_float(((unsigned)(unsigned short)xv[u]) << 16);
                sum += xs[0]*w0.x + xs[1]*w0.y + xs[2]*w0.z + xs[3]*w0.w
                     + xs[4]*w1.x + xs[5]*w1.y + xs[6]*w1.z + xs[7]*w1.w;
            }
            #pragma unroll
            for (int off = 32; off > 0; off >>= 1) sum += __shfl_xor(sum, off);
            if (lane == 0) {
                float2 v; v.x = sum; v.y = 0.f;
                ((float2*)out)[((size_t)b * F_BINS + 1024) * T_FR + t] = v;
            }
        }
        return;
    }

    const int quad  = lane >> 4;
    const int l15   = lane & 15;
    const int waveM = wave >> 2;   // 2(M) x 4(N) wave grid; per-wave out 64m x 64n
    const int waveN = wave & 3;

    // XCD swizzle: 864 = 8 x 108; bn == XCD id -> B-panel L2-resident per XCD
    const int bn = blockIdx.x & 7;
    const int bm = blockIdx.x >> 3;

    // ---- staging addressing (per-lane) ----
    const int l4 = lane >> 2, lc = lane & 3;
    const int swz = (lc ^ (l4 & 3)) * 8;       // pre-swizzled source chunk (elems)
    int am = bm * 128 + wave * 16 + l4;
    if (am > M_TOT - 1) am = M_TOT - 1;        // clamp; masked at store
    const int ab_ = am / T_FR, at_ = am - ab_ * T_FR;
    const int aoff  = ab_ * LPP + at_ * HOPSZ + swz;
    const int bnrow = bn * 256 + wave * 32 + l4;            // q=0 rows (<= 2047)
    const int boff0 = bnrow * K_TOT + swz;
    const int boff1 = (bnrow + 16) * K_TOT + swz;
    const int adst  = wave * 512;              // shorts, within A buffer (4096)
    const int bdst  = wave * 1024;             // shorts, within B buffer (8192)

    // ---- read addressing (shorts) ----
    const int rchunk = (quad ^ (l15 & 3)) * 8;
    const int ara = (waveM * 64 + l15) * 32 + rchunk;   // + jm*512, + buf*4096
    const int bra = (waveN * 64 + l15) * 32 + rchunk;   // + jn*512, + 12288 + buf*8192

#define STAGE(BUF, K0) { \
        glds16(xp + aoff  + (K0), &lds[(BUF) * 4096 + adst]); \
        glds16(wb + boff0 + (K0), &lds[12288 + (BUF) * 8192 + bdst]); \
        glds16(wb + boff1 + (K0), &lds[12288 + (BUF) * 8192 + bdst + 512]); }
#define READS(BUF) { \
        _Pragma("unroll") for (int i = 0; i < 4; ++i) \
            wf[i] = *(const short8*)&lds[12288 + (BUF) * 8192 + bra + i * 512]; \
        _Pragma("unroll") for (int j = 0; j < 4; ++j) \
            xf[j] = *(const short8*)&lds[(BUF) * 4096 + ara + j * 512]; }

    short8 xf[4], wf[4];
    floatx4 acc[4][4] = {};   // acc[i = n'-block][j = m-block]

    // prologue: stage tiles 0 and 1
    STAGE(0, 0);
    STAGE(1, 32);
    VMW(3);        // tile 0 landed (3 of 6 outstanding)
    BARRIER;

    int r0 = 0, r1 = 1, r2 = 2;
    #pragma unroll 1
    for (int t = 0; t < NT_K; ++t) {
        if (t < NT_K - 2) STAGE(r2, (t + 2) * 32);
        SCHED0;
        READS(r0);
        SP1;
        #pragma unroll
        for (int i = 0; i < 4; ++i)
            #pragma unroll
            for (int j = 0; j < 4; ++j)
                acc[i][j] = __builtin_amdgcn_mfma_f32_16x16x32_bf16(wf[i], xf[j], acc[i][j], 0, 0, 0);
        SP0;
        if (t < NT_K - 1) {
            if (t < NT_K - 2) { VMW(3); } else { VMW(0); }
            BARRIER;
        }
        int tmp = r0; r0 = r1; r1 = r2; r2 = tmp;
    }

    // epilogue: C^T; lane&15 = m (consecutive t), regs = consecutive n' = (k, re/im)
    float2* __restrict__ out2 = (float2*)out;
    #pragma unroll
    for (int j = 0; j < 4; ++j) {
        int m = bm * 128 + waveM * 64 + j * 16 + l15;
        if (m >= M_TOT) continue;
        int b = m / T_FR, t = m - b * T_FR;
        long tbase = (long)b * (F_BINS * T_FR) + t;
        #pragma unroll
        for (int i = 0; i < 4; ++i) {
            int nb = bn * 256 + waveN * 64 + i * 16 + quad * 4;
            #pragma unroll
            for (int p = 0; p < 2; ++p) {
                int k = (nb + 2 * p) >> 1;
                float2 v; v.x = acc[i][j][2 * p]; v.y = -acc[i][j][2 * p + 1];
                out2[tbase + (long)k * T_FR] = v;
            }
        }
    }
}

extern "C" void kernel_launch(void* const* d_in, const int* in_sizes, int n_in,
                              void* d_out, int out_size, void* d_ws, size_t ws_size,
                              hipStream_t stream) {
    const float* x    = (const float*)d_in[0];
    const float* wcos = (const float*)d_in[1];
    const float* wsin = (const float*)d_in[2];
    float* out = (float*)d_out;

    // ws: xp bf16 [32][LPP] then wb bf16 [2048][2048]  (~22.6 MB)
    __hip_bfloat16* xp = (__hip_bfloat16*)d_ws;
    __hip_bfloat16* wb = (__hip_bfloat16*)((char*)d_ws + (size_t)BATCH * LPP * sizeof(__hip_bfloat16));

    k_prep<<<XBLOCKS + WBLOCKS, 256, 0, stream>>>(x, wcos, wsin, xp, wb);
    k_gemm<<<GEMM_BLOCKS + NYQ_BLOCKS, 512, 0, stream>>>(xp, wb, wcos, out);
}

// Round 4
// 272.145 us; speedup vs baseline: 1.0080x; 1.0080x over previous
//
#include <hip/hip_runtime.h>
#include <hip/hip_bf16.h>

// ---- problem constants ----
#define L_IN   220500
#define PADK   1024
#define LP     222548            // L_IN + 2048 (reflect-padded length)
#define LPP    222560            // LP rounded up to 16B-aligned rows
#define BATCH  32
#define HOPSZ  512
#define T_FR   431               // frames per batch
#define F_BINS 1025
#define M_TOT  (BATCH * T_FR)    // 13792 frames
#define N_GEMM 2048              // interleaved rows n' = 2k + c for k = 0..1023
#define K_TOT  2048
#define NT_K   64                // K tiles of 32
#define GEMM_BLOCKS 864          // 108 m-tiles (BM=128) x 8 n-tiles (BN=256)
#define NYQ_BLOCKS  48
#define XBLOCKS 3488             // 109 per batch x 32
#define WBLOCKS 2048

typedef short short8 __attribute__((ext_vector_type(8)));
typedef float floatx4 __attribute__((ext_vector_type(4)));

__device__ __forceinline__ void glds16(const void* g, void* l) {
    __builtin_amdgcn_global_load_lds(
        (const __attribute__((address_space(1))) void*)g,
        (__attribute__((address_space(3))) void*)l, 16, 0, 0);
}

__device__ __forceinline__ short f2bf(float f) {
    __hip_bfloat16 h = __float2bfloat16(f);
    return *reinterpret_cast<short*>(&h);
}

// ---- pass 1: fused reflect-pad x->bf16 (blocks 0..3487) + weight interleave (3488..5535)
__global__ void k_prep(const float* __restrict__ x,
                       const float* __restrict__ wcos, const float* __restrict__ wsin,
                       __hip_bfloat16* __restrict__ xp, __hip_bfloat16* __restrict__ wb) {
    int blk = blockIdx.x;
    if (blk < XBLOCKS) {
        int b = blk / 109, ix = blk - b * 109;
        int i0 = (ix * 256 + threadIdx.x) * 8;
        if (i0 >= LP) return;
        const float* xb = x + (size_t)b * L_IN;
        __hip_bfloat16* xpb = xp + (size_t)b * LPP;
        if (i0 >= PADK && i0 + 8 <= PADK + L_IN) {
            const float4* s4 = (const float4*)(xb + (i0 - PADK));
            float4 a = s4[0], d = s4[1];
            short8 o;
            o[0]=f2bf(a.x); o[1]=f2bf(a.y); o[2]=f2bf(a.z); o[3]=f2bf(a.w);
            o[4]=f2bf(d.x); o[5]=f2bf(d.y); o[6]=f2bf(d.z); o[7]=f2bf(d.w);
            *(short8*)((short*)xpb + i0) = o;
        } else {
            for (int u = 0; u < 8; ++u) {
                int i = i0 + u;
                if (i >= LP) break;
                int j = i - PADK;
                if (j < 0) j = -j;
                if (j >= L_IN) j = 2 * L_IN - 2 - j;
                xpb[i] = __float2bfloat16(xb[j]);
            }
        }
    } else {
        int i0 = ((blk - XBLOCKS) * 256 + threadIdx.x) * 8;   // < 2048*2048 exactly
        int np = i0 >> 11;
        int k  = i0 & (K_TOT - 1);
        int kf = np >> 1;
        const float* src = ((np & 1) ? wsin : wcos) + (size_t)kf * K_TOT + k;
        float4 a = ((const float4*)src)[0], d = ((const float4*)src)[1];
        short8 o;
        o[0]=f2bf(a.x); o[1]=f2bf(a.y); o[2]=f2bf(a.z); o[3]=f2bf(a.w);
        o[4]=f2bf(d.x); o[5]=f2bf(d.y); o[6]=f2bf(d.z); o[7]=f2bf(d.w);
        *(short8*)((short*)wb + i0) = o;
    }
}

// ---- pass 2: 128x256 (BM x BN) bf16 MFMA GEMM (C^T), BK=32, triple-buffered LDS,
// 1 barrier/tile, counted vmcnt(3), 2 blocks/CU (4 waves/SIMD).
//
// LDS 72 KiB: A[3][128][32] shorts at 0 (3x4096), B[3][256][32] at 12288 (3x8192).
// Swizzle (rows are 64B = 4 x 16B chunks): LDS[row][c] = global[row][c ^ ((row>>1)&3)].
// KEY FIX vs prior round: XOR key is (row>>1)&3, NOT row&3. LDS services waves in
// 16-lane groups; with key=(row&3) the even-row lanes of a group hit only 2 of 4
// chunk columns (4/4/0/0 per bank-half -> 2-way conflict, measured 1.4e7). With
// key=(row>>1)&3 each (bank-half, chunk) pair gets exactly 2 lanes per 16-lane
// group = the b128 floor -> conflict-free.
#define BARRIER { asm volatile("" ::: "memory"); __builtin_amdgcn_s_barrier(); asm volatile("" ::: "memory"); }
#define VMW(N)  asm volatile("s_waitcnt vmcnt(" #N ")" ::: "memory")
#define SCHED0  __builtin_amdgcn_sched_barrier(0)
#define SP1     __builtin_amdgcn_s_setprio(1)
#define SP0     __builtin_amdgcn_s_setprio(0)

__global__ __launch_bounds__(512, 4) void k_gemm(
    const __hip_bfloat16* __restrict__ xp,
    const __hip_bfloat16* __restrict__ wb,
    const float* __restrict__ wcos,
    float* __restrict__ out) {

    __shared__ short lds[36864];   // 72 KiB

    const int tid  = threadIdx.x;
    const int wave = tid >> 6;
    const int lane = tid & 63;

    // ---- Nyquist tail blocks: k=1024 row (wsin==0 -> imag==0) ----
    if (blockIdx.x >= GEMM_BLOCKS) {
        const int gw = (blockIdx.x - GEMM_BLOCKS) * 8 + wave;   // 0..383
        const float* wr = wcos + (size_t)1024 * K_TOT;
        for (int f = gw; f < M_TOT; f += NYQ_BLOCKS * 8) {
            int b = f / T_FR, t = f - b * T_FR;
            const __hip_bfloat16* xr = xp + (size_t)b * LPP + t * HOPSZ;
            float sum = 0.f;
            #pragma unroll
            for (int i = 0; i < 4; ++i) {
                int s = i * 512 + lane * 8;
                short8 xv = *(const short8*)((const short*)xr + s);
                const float4* wv = (const float4*)(wr + s);
                float4 w0 = wv[0], w1 = wv[1];
                float xs[8];
                #pragma unroll
                for (int u = 0; u < 8; ++u)
                    xs[u] = __uint_as_float(((unsigned)(unsigned short)xv[u]) << 16);
                sum += xs[0]*w0.x + xs[1]*w0.y + xs[2]*w0.z + xs[3]*w0.w
                     + xs[4]*w1.x + xs[5]*w1.y + xs[6]*w1.z + xs[7]*w1.w;
            }
            #pragma unroll
            for (int off = 32; off > 0; off >>= 1) sum += __shfl_xor(sum, off);
            if (lane == 0) {
                float2 v; v.x = sum; v.y = 0.f;
                ((float2*)out)[((size_t)b * F_BINS + 1024) * T_FR + t] = v;
            }
        }
        return;
    }

    const int quad  = lane >> 4;
    const int l15   = lane & 15;
    const int waveM = wave >> 2;   // 2(M) x 4(N) wave grid; per-wave out 64m x 64n
    const int waveN = wave & 3;

    // XCD swizzle: 864 = 8 x 108; bn == XCD id -> B-panel L2-resident per XCD
    const int bn = blockIdx.x & 7;
    const int bm = blockIdx.x >> 3;

    // ---- staging addressing (per-lane) ----
    const int l4 = lane >> 2, lc = lane & 3;
    // linear LDS dest chunk lc of row l4 must hold global chunk lc ^ s(row),
    // s(row) = (row>>1)&3 = (lane>>3)&3
    const int swz = (lc ^ ((l4 >> 1) & 3)) * 8;
    int am = bm * 128 + wave * 16 + l4;
    if (am > M_TOT - 1) am = M_TOT - 1;        // clamp; masked at store
    const int ab_ = am / T_FR, at_ = am - ab_ * T_FR;
    const int aoff  = ab_ * LPP + at_ * HOPSZ + swz;
    const int bnrow = bn * 256 + wave * 32 + l4;            // q=0 rows (<= 2047)
    const int boff0 = bnrow * K_TOT + swz;
    const int boff1 = (bnrow + 16) * K_TOT + swz;           // s(row+16) == s(row)
    const int adst  = wave * 512;              // shorts, within A buffer (4096)
    const int bdst  = wave * 1024;             // shorts, within B buffer (8192)

    // ---- read addressing (shorts): chunk = quad ^ s(row), s = (l15>>1)&3
    // (invariant under +16-row steps jm/jn and wave offsets)
    const int rchunk = (quad ^ ((l15 >> 1) & 3)) * 8;
    const int ara = (waveM * 64 + l15) * 32 + rchunk;   // + jm*512, + buf*4096
    const int bra = (waveN * 64 + l15) * 32 + rchunk;   // + jn*512, + 12288 + buf*8192

#define STAGE(BUF, K0) { \
        glds16(xp + aoff  + (K0), &lds[(BUF) * 4096 + adst]); \
        glds16(wb + boff0 + (K0), &lds[12288 + (BUF) * 8192 + bdst]); \
        glds16(wb + boff1 + (K0), &lds[12288 + (BUF) * 8192 + bdst + 512]); }
#define READS(BUF) { \
        _Pragma("unroll") for (int i = 0; i < 4; ++i) \
            wf[i] = *(const short8*)&lds[12288 + (BUF) * 8192 + bra + i * 512]; \
        _Pragma("unroll") for (int j = 0; j < 4; ++j) \
            xf[j] = *(const short8*)&lds[(BUF) * 4096 + ara + j * 512]; }

    short8 xf[4], wf[4];
    floatx4 acc[4][4] = {};   // acc[i = n'-block][j = m-block]

    // prologue: stage tiles 0 and 1
    STAGE(0, 0);
    STAGE(1, 32);
    VMW(3);        // tile 0 landed (3 of 6 outstanding)
    BARRIER;

    int r0 = 0, r1 = 1, r2 = 2;
    #pragma unroll 1
    for (int t = 0; t < NT_K; ++t) {
        if (t < NT_K - 2) STAGE(r2, (t + 2) * 32);
        SCHED0;
        READS(r0);
        SP1;
        #pragma unroll
        for (int i = 0; i < 4; ++i)
            #pragma unroll
            for (int j = 0; j < 4; ++j)
                acc[i][j] = __builtin_amdgcn_mfma_f32_16x16x32_bf16(wf[i], xf[j], acc[i][j], 0, 0, 0);
        SP0;
        if (t < NT_K - 1) {
            if (t < NT_K - 2) { VMW(3); } else { VMW(0); }
            BARRIER;
        }
        int tmp = r0; r0 = r1; r1 = r2; r2 = tmp;
    }

    // epilogue: C^T; lane&15 = m (consecutive t), regs = consecutive n' = (k, re/im)
    float2* __restrict__ out2 = (float2*)out;
    #pragma unroll
    for (int j = 0; j < 4; ++j) {
        int m = bm * 128 + waveM * 64 + j * 16 + l15;
        if (m >= M_TOT) continue;
        int b = m / T_FR, t = m - b * T_FR;
        long tbase = (long)b * (F_BINS * T_FR) + t;
        #pragma unroll
        for (int i = 0; i < 4; ++i) {
            int nb = bn * 256 + waveN * 64 + i * 16 + quad * 4;
            #pragma unroll
            for (int p = 0; p < 2; ++p) {
                int k = (nb + 2 * p) >> 1;
                float2 v; v.x = acc[i][j][2 * p]; v.y = -acc[i][j][2 * p + 1];
                out2[tbase + (long)k * T_FR] = v;
            }
        }
    }
}

extern "C" void kernel_launch(void* const* d_in, const int* in_sizes, int n_in,
                              void* d_out, int out_size, void* d_ws, size_t ws_size,
                              hipStream_t stream) {
    const float* x    = (const float*)d_in[0];
    const float* wcos = (const float*)d_in[1];
    const float* wsin = (const float*)d_in[2];
    float* out = (float*)d_out;

    // ws: xp bf16 [32][LPP] then wb bf16 [2048][2048]  (~22.6 MB)
    __hip_bfloat16* xp = (__hip_bfloat16*)d_ws;
    __hip_bfloat16* wb = (__hip_bfloat16*)((char*)d_ws + (size_t)BATCH * LPP * sizeof(__hip_bfloat16));

    k_prep<<<XBLOCKS + WBLOCKS, 256, 0, stream>>>(x, wcos, wsin, xp, wb);
    k_gemm<<<GEMM_BLOCKS + NYQ_BLOCKS, 512, 0, stream>>>(xp, wb, wcos, out);
}

// Round 5
// 270.595 us; speedup vs baseline: 1.0138x; 1.0057x over previous
//
#include <hip/hip_runtime.h>
#include <hip/hip_bf16.h>

// ---- problem constants ----
#define L_IN   220500
#define PADK   1024
#define LP     222548            // L_IN + 2048 (reflect-padded length)
#define LPP    222560            // LP rounded up to 16B-aligned rows
#define BATCH  32
#define HOPSZ  512
#define T_FR   431               // frames per batch
#define F_BINS 1025
#define M_TOT  (BATCH * T_FR)    // 13792 frames
#define N_GEMM 2048              // interleaved rows n' = 2k + c for k = 0..1023
#define K_TOT  2048
#define NT_K   64                // K tiles of 32
#define GEMM_BLOCKS 864          // 108 m-tiles (BM=128) x 8 n-tiles (BN=256)
#define NYQ_BLOCKS  48
#define XBLOCKS 3488             // 109 per batch x 32
#define WBLOCKS 2048

typedef short short8 __attribute__((ext_vector_type(8)));
typedef float floatx4 __attribute__((ext_vector_type(4)));

__device__ __forceinline__ void glds16(const void* g, void* l) {
    __builtin_amdgcn_global_load_lds(
        (const __attribute__((address_space(1))) void*)g,
        (__attribute__((address_space(3))) void*)l, 16, 0, 0);
}

__device__ __forceinline__ short f2bf(float f) {
    __hip_bfloat16 h = __float2bfloat16(f);
    return *reinterpret_cast<short*>(&h);
}

// ---- pass 1: fused reflect-pad x->bf16 (blocks 0..3487) + weight interleave (3488..5535)
__global__ void k_prep(const float* __restrict__ x,
                       const float* __restrict__ wcos, const float* __restrict__ wsin,
                       __hip_bfloat16* __restrict__ xp, __hip_bfloat16* __restrict__ wb) {
    int blk = blockIdx.x;
    if (blk < XBLOCKS) {
        int b = blk / 109, ix = blk - b * 109;
        int i0 = (ix * 256 + threadIdx.x) * 8;
        if (i0 >= LP) return;
        const float* xb = x + (size_t)b * L_IN;
        __hip_bfloat16* xpb = xp + (size_t)b * LPP;
        if (i0 >= PADK && i0 + 8 <= PADK + L_IN) {
            const float4* s4 = (const float4*)(xb + (i0 - PADK));
            float4 a = s4[0], d = s4[1];
            short8 o;
            o[0]=f2bf(a.x); o[1]=f2bf(a.y); o[2]=f2bf(a.z); o[3]=f2bf(a.w);
            o[4]=f2bf(d.x); o[5]=f2bf(d.y); o[6]=f2bf(d.z); o[7]=f2bf(d.w);
            *(short8*)((short*)xpb + i0) = o;
        } else {
            for (int u = 0; u < 8; ++u) {
                int i = i0 + u;
                if (i >= LP) break;
                int j = i - PADK;
                if (j < 0) j = -j;
                if (j >= L_IN) j = 2 * L_IN - 2 - j;
                xpb[i] = __float2bfloat16(xb[j]);
            }
        }
    } else {
        int i0 = ((blk - XBLOCKS) * 256 + threadIdx.x) * 8;   // < 2048*2048 exactly
        int np = i0 >> 11;
        int k  = i0 & (K_TOT - 1);
        int kf = np >> 1;
        const float* src = ((np & 1) ? wsin : wcos) + (size_t)kf * K_TOT + k;
        float4 a = ((const float4*)src)[0], d = ((const float4*)src)[1];
        short8 o;
        o[0]=f2bf(a.x); o[1]=f2bf(a.y); o[2]=f2bf(a.z); o[3]=f2bf(a.w);
        o[4]=f2bf(d.x); o[5]=f2bf(d.y); o[6]=f2bf(d.z); o[7]=f2bf(d.w);
        *(short8*)((short*)wb + i0) = o;
    }
}

// ---- pass 2: 128x256 bf16 MFMA GEMM (C^T), BK=32, triple-buffered LDS, 2 blocks/CU.
// ROUND-5 CHANGE (de-burst): the barrier-released read-burst/MFMA-burst convoy is
// the diagnosed stall (LDS storm delays glds retirement -> vmcnt stalls both
// co-resident blocks in lockstep). Fix: (a) VMW moved BEFORE the compute region so
// the wait is covered by the other block's MFMAs, (b) the 8 ds_read_b128 are woven
// among the 16 MFMAs via sched_group_barrier (CK v3 pattern), reads ordered to
// feed each MFMA group just-in-time.
#define BARRIER { asm volatile("" ::: "memory"); __builtin_amdgcn_s_barrier(); asm volatile("" ::: "memory"); }
#define VMW(N)  asm volatile("s_waitcnt vmcnt(" #N ")" ::: "memory")
#define SGB(M,N) __builtin_amdgcn_sched_group_barrier((M), (N), 0)
#define SP1     __builtin_amdgcn_s_setprio(1)
#define SP0     __builtin_amdgcn_s_setprio(0)

__global__ __launch_bounds__(512, 4) void k_gemm(
    const __hip_bfloat16* __restrict__ xp,
    const __hip_bfloat16* __restrict__ wb,
    const float* __restrict__ wcos,
    float* __restrict__ out) {

    __shared__ short lds[36864];   // 72 KiB

    const int tid  = threadIdx.x;
    const int wave = tid >> 6;
    const int lane = tid & 63;

    // ---- Nyquist tail blocks: k=1024 row (wsin==0 -> imag==0) ----
    if (blockIdx.x >= GEMM_BLOCKS) {
        const int gw = (blockIdx.x - GEMM_BLOCKS) * 8 + wave;   // 0..383
        const float* wr = wcos + (size_t)1024 * K_TOT;
        for (int f = gw; f < M_TOT; f += NYQ_BLOCKS * 8) {
            int b = f / T_FR, t = f - b * T_FR;
            const __hip_bfloat16* xr = xp + (size_t)b * LPP + t * HOPSZ;
            float sum = 0.f;
            #pragma unroll
            for (int i = 0; i < 4; ++i) {
                int s = i * 512 + lane * 8;
                short8 xv = *(const short8*)((const short*)xr + s);
                const float4* wv = (const float4*)(wr + s);
                float4 w0 = wv[0], w1 = wv[1];
                float xs[8];
                #pragma unroll
                for (int u = 0; u < 8; ++u)
                    xs[u] = __uint_as_float(((unsigned)(unsigned short)xv[u]) << 16);
                sum += xs[0]*w0.x + xs[1]*w0.y + xs[2]*w0.z + xs[3]*w0.w
                     + xs[4]*w1.x + xs[5]*w1.y + xs[6]*w1.z + xs[7]*w1.w;
            }
            #pragma unroll
            for (int off = 32; off > 0; off >>= 1) sum += __shfl_xor(sum, off);
            if (lane == 0) {
                float2 v; v.x = sum; v.y = 0.f;
                ((float2*)out)[((size_t)b * F_BINS + 1024) * T_FR + t] = v;
            }
        }
        return;
    }

    const int quad  = lane >> 4;
    const int l15   = lane & 15;
    const int waveM = wave >> 2;   // 2(M) x 4(N) wave grid; per-wave out 64m x 64n
    const int waveN = wave & 3;

    // XCD swizzle: 864 = 8 x 108; bn == XCD id -> B-panel L2-resident per XCD
    const int bn = blockIdx.x & 7;
    const int bm = blockIdx.x >> 3;

    // ---- staging addressing (per-lane) ----
    const int l4 = lane >> 2, lc = lane & 3;
    // linear LDS dest chunk lc of row l4 holds global chunk lc ^ s(row), s=(row>>1)&3
    const int swz = (lc ^ ((l4 >> 1) & 3)) * 8;
    int am = bm * 128 + wave * 16 + l4;
    if (am > M_TOT - 1) am = M_TOT - 1;        // clamp; masked at store
    const int ab_ = am / T_FR, at_ = am - ab_ * T_FR;
    const int aoff  = ab_ * LPP + at_ * HOPSZ + swz;
    const int bnrow = bn * 256 + wave * 32 + l4;            // q=0 rows (<= 2047)
    const int boff0 = bnrow * K_TOT + swz;
    const int boff1 = (bnrow + 16) * K_TOT + swz;           // s(row+16) == s(row)
    const int adst  = wave * 512;              // shorts, within A buffer (4096)
    const int bdst  = wave * 1024;             // shorts, within B buffer (8192)

    // ---- read addressing (shorts): chunk = quad ^ s(row), s = (l15>>1)&3
    const int rchunk = (quad ^ ((l15 >> 1) & 3)) * 8;
    const int ara = (waveM * 64 + l15) * 32 + rchunk;   // + jm*512, + buf*4096
    const int bra = (waveN * 64 + l15) * 32 + rchunk;   // + jn*512, + 12288 + buf*8192

#define STAGE(BUF, K0) { \
        glds16(xp + aoff  + (K0), &lds[(BUF) * 4096 + adst]); \
        glds16(wb + boff0 + (K0), &lds[12288 + (BUF) * 8192 + bdst]); \
        glds16(wb + boff1 + (K0), &lds[12288 + (BUF) * 8192 + bdst + 512]); }

    short8 xf[4], wf[4];
    floatx4 acc[4][4] = {};   // acc[i = n'-block][j = m-block]

    // prologue: stage tiles 0 and 1
    STAGE(0, 0);
    STAGE(1, 32);
    VMW(3);        // tile 0 landed (3 of 6 outstanding)
    BARRIER;

    int r0 = 0, r1 = 1, r2 = 2;
    #pragma unroll 1
    for (int t = 0; t < NT_K; ++t) {
        if (t < NT_K - 2) STAGE(r2, (t + 2) * 32);
        // early wait: tile t+1 landed; overlapped by the co-resident block's MFMAs
        if (t < NT_K - 2)      { VMW(3); }
        else if (t == NT_K - 2){ VMW(0); }
        SP1;
        // reads ordered to feed MFMA groups just-in-time: wf0,xf0 -> M0x; wf{1,2,3} late
        wf[0] = *(const short8*)&lds[12288 + r0 * 8192 + bra];
        #pragma unroll
        for (int j = 0; j < 4; ++j)
            xf[j] = *(const short8*)&lds[r0 * 4096 + ara + j * 512];
        #pragma unroll
        for (int i = 1; i < 4; ++i)
            wf[i] = *(const short8*)&lds[12288 + r0 * 8192 + bra + i * 512];
        #pragma unroll
        for (int i = 0; i < 4; ++i)
            #pragma unroll
            for (int j = 0; j < 4; ++j)
                acc[i][j] = __builtin_amdgcn_mfma_f32_16x16x32_bf16(wf[i], xf[j], acc[i][j], 0, 0, 0);
        // sched_group_barrier interleave: weave the 8 ds_reads into the 16 MFMAs
        // (DS_READ=0x100, MFMA=0x8): {DS2 M1}{DS1 M1}x3 {DS1 M4}x3
        SGB(0x100, 2); SGB(0x8, 1);
        SGB(0x100, 1); SGB(0x8, 1);
        SGB(0x100, 1); SGB(0x8, 1);
        SGB(0x100, 1); SGB(0x8, 1);
        SGB(0x100, 1); SGB(0x8, 4);
        SGB(0x100, 1); SGB(0x8, 4);
        SGB(0x100, 1); SGB(0x8, 4);
        SP0;
        if (t < NT_K - 1) BARRIER;
        int tmp = r0; r0 = r1; r1 = r2; r2 = tmp;
    }

    // epilogue: C^T; lane&15 = m (consecutive t), regs = consecutive n' = (k, re/im)
    float2* __restrict__ out2 = (float2*)out;
    #pragma unroll
    for (int j = 0; j < 4; ++j) {
        int m = bm * 128 + waveM * 64 + j * 16 + l15;
        if (m >= M_TOT) continue;
        int b = m / T_FR, t = m - b * T_FR;
        long tbase = (long)b * (F_BINS * T_FR) + t;
        #pragma unroll
        for (int i = 0; i < 4; ++i) {
            int nb = bn * 256 + waveN * 64 + i * 16 + quad * 4;
            #pragma unroll
            for (int p = 0; p < 2; ++p) {
                int k = (nb + 2 * p) >> 1;
                float2 v; v.x = acc[i][j][2 * p]; v.y = -acc[i][j][2 * p + 1];
                out2[tbase + (long)k * T_FR] = v;
            }
        }
    }
}

extern "C" void kernel_launch(void* const* d_in, const int* in_sizes, int n_in,
                              void* d_out, int out_size, void* d_ws, size_t ws_size,
                              hipStream_t stream) {
    const float* x    = (const float*)d_in[0];
    const float* wcos = (const float*)d_in[1];
    const float* wsin = (const float*)d_in[2];
    float* out = (float*)d_out;

    // ws: xp bf16 [32][LPP] then wb bf16 [2048][2048]  (~22.6 MB)
    __hip_bfloat16* xp = (__hip_bfloat16*)d_ws;
    __hip_bfloat16* wb = (__hip_bfloat16*)((char*)d_ws + (size_t)BATCH * LPP * sizeof(__hip_bfloat16));

    k_prep<<<XBLOCKS + WBLOCKS, 256, 0, stream>>>(x, wcos, wsin, xp, wb);
    k_gemm<<<GEMM_BLOCKS + NYQ_BLOCKS, 512, 0, stream>>>(xp, wb, wcos, out);
}

// Round 6
// 223.566 us; speedup vs baseline: 1.2271x; 1.2104x over previous
//
#include <hip/hip_runtime.h>
#include <hip/hip_bf16.h>

// ---- problem constants ----
#define L_IN   220500
#define BATCH  32
#define T_FR   431               // frames per batch
#define F_BINS 1025
#define M_TOT  (BATCH * T_FR)    // 13792 frames
#define KROW   2048              // Y row: Y0[512] | Y2[512] | Y1re[512] | Y1im[512]
// radix-4 factorization: X[4u+r] = sum_q Y_r[q] e^{-2pi i (4u+r) q / 2048}
//   Y0 = a0+a1+a2+a3 ; Y2 = a0-a1+a2-a3 ; Y1 = (a0-a2) + i(a3-a1),  a_p = win[512p+q]*x[.]
//   r=3 outputs via conjugate symmetry of r=1 ; k=1024 = sum Y0*(-1)^q (free).
// weights (pure trig, bf16): g0g2 = 1024 rows x 512 ; g1 = 1024 rows x 1024
#define WG02   524288
#define WG1    1048576
#define GEMM_BLOCKS 864          // 108 bm (BM=128) x 8 bn (256-col tiles)
#define NYQ_BLOCKS  48
#define BF_BLOCKS   1728         // 54 per batch x 32, 8 frames/block
#define WGT_BLOCKS  384          // (WG02+WG1)/4096

typedef short short8 __attribute__((ext_vector_type(8)));
typedef float floatx4 __attribute__((ext_vector_type(4)));

__device__ __forceinline__ void glds16(const void* g, void* l) {
    __builtin_amdgcn_global_load_lds(
        (const __attribute__((address_space(1))) void*)g,
        (__attribute__((address_space(3))) void*)l, 16, 0, 0);
}

__device__ __forceinline__ short f2bf(float f) {
    __hip_bfloat16 h = __float2bfloat16(f);
    return *reinterpret_cast<short*>(&h);
}

// ---- pass 1: butterfly (blocks 0..1727) + trig weight gen (1728..2111) ----
__global__ __launch_bounds__(512) void k_prep(const float* __restrict__ x,
        const float* __restrict__ wcos,
        __hip_bfloat16* __restrict__ yb, __hip_bfloat16* __restrict__ w2) {
    const int blk = blockIdx.x, tid = threadIdx.x;
    if (blk < BF_BLOCKS) {
        int b = blk / 54, rem = blk - b * 54;
        int t = rem * 8 + (tid >> 6);
        if (t >= T_FR) return;
        int q = (tid & 63) * 8;
        const float* xb = x + (size_t)b * L_IN;
        float a[4][8];
        #pragma unroll
        for (int p = 0; p < 4; ++p) {
            // window = wcos row 0 (win[s]*cos(0))
            const float4* wv = (const float4*)(wcos + 512 * p + q);
            float4 w0 = wv[0], w1 = wv[1];
            float w[8] = {w0.x,w0.y,w0.z,w0.w,w1.x,w1.y,w1.z,w1.w};
            int jb = t * 512 + 512 * p + q - 1024;     // reflect-padded origin
            if (jb >= 0 && jb <= L_IN - 8) {
                const float4* s4 = (const float4*)(xb + jb);
                float4 v0 = s4[0], v1 = s4[1];
                float v[8] = {v0.x,v0.y,v0.z,v0.w,v1.x,v1.y,v1.z,v1.w};
                #pragma unroll
                for (int u = 0; u < 8; ++u) a[p][u] = v[u] * w[u];
            } else {
                #pragma unroll
                for (int u = 0; u < 8; ++u) {
                    int j = jb + u;
                    if (j < 0) j = -j;
                    if (j >= L_IN) j = 2 * L_IN - 2 - j;
                    a[p][u] = xb[j] * w[u];
                }
            }
        }
        short8 y0, y2, yre, yim;
        #pragma unroll
        for (int u = 0; u < 8; ++u) {
            y0[u]  = f2bf(a[0][u] + a[1][u] + a[2][u] + a[3][u]);
            y2[u]  = f2bf(a[0][u] - a[1][u] + a[2][u] - a[3][u]);
            yre[u] = f2bf(a[0][u] - a[2][u]);
            yim[u] = f2bf(a[3][u] - a[1][u]);
        }
        short* yr = (short*)yb + (size_t)(b * T_FR + t) * KROW;
        *(short8*)(yr + q)        = y0;
        *(short8*)(yr + 512 + q)  = y2;
        *(short8*)(yr + 1024 + q) = yre;
        *(short8*)(yr + 1536 + q) = yim;
    } else {
        // weights; columns come in (Re, Im) pairs, signs folded so epilogue stores raw.
        long e0 = (long)(blk - BF_BLOCKS) * 4096 + (long)tid * 8;
        short8 o;
        const float SC = 3.0679615757712823e-3f;   // 2*pi/2048
        if (e0 < WG02) {           // g0 (rows 0..511, k=4u) / g2 (rows 512..1023, k=4u+2)
            int n = (int)(e0 >> 9), q0 = (int)(e0 & 511);
            int c = n & 1;
            int k = (n < 512) ? 4 * (n >> 1) : 4 * ((n - 512) >> 1) + 2;
            #pragma unroll
            for (int u = 0; u < 8; ++u) {
                int ph = (k * (q0 + u)) & 2047;
                float s, cc;
                __sincosf((float)ph * SC, &s, &cc);
                o[u] = f2bf(c ? -s : cc);          // ReX = sum Y cos ; ImX = -sum Y sin
            }
        } else {                   // g1: rows n=2v+c, K=1024 over (Yre[512] ++ Yim[512])
            long f = e0 - WG02;
            int n = (int)(f >> 10), q0 = (int)(f & 1023);
            int c = n & 1, v = n >> 1;
            int half = q0 >> 9, qq = q0 & 511;
            int k = (v < 256) ? 4 * v + 1 : 3069 - 4 * v;   // v>=256: k' = 2048-(4(v-256)+3)
            #pragma unroll
            for (int u = 0; u < 8; ++u) {
                int ph = (k * (qq + u)) & 2047;
                float s, cc;
                __sincosf((float)ph * SC, &s, &cc);
                float val;
                if (v < 256) val = c ? (half ? cc : -s) : (half ? s : cc);
                else         val = c ? (half ? -cc : s) : (half ? s : cc); // conj branch
                o[u] = f2bf(val);
            }
        }
        *(short8*)((short*)w2 + e0) = o;
    }
}

// ---- pass 2: factored GEMM. Per bn: groups g0/g2 (K=512) and g1 (K=1024).
// Same verified machinery as prior round: BM=128/BN=256, BK=32, triple-buffered LDS,
// (row>>1)&3 chunk swizzle (0 conflicts measured), counted vmcnt(3), 2 blocks/CU.
#define BARRIER { asm volatile("" ::: "memory"); __builtin_amdgcn_s_barrier(); asm volatile("" ::: "memory"); }
#define VMW(N)  asm volatile("s_waitcnt vmcnt(" #N ")" ::: "memory")
#define SP1     __builtin_amdgcn_s_setprio(1)
#define SP0     __builtin_amdgcn_s_setprio(0)

__global__ __launch_bounds__(512, 2) void k_gemm(
    const __hip_bfloat16* __restrict__ yb,
    const __hip_bfloat16* __restrict__ w2,
    float* __restrict__ out) {

    __shared__ short lds[36864];   // 72 KiB
    const int tid = threadIdx.x, wave = tid >> 6, lane = tid & 63;

    // ---- Nyquist tail blocks: k=1024 = sum_q Y0[q]*(-1)^q ----
    if (blockIdx.x >= GEMM_BLOCKS) {
        const int gw = (blockIdx.x - GEMM_BLOCKS) * 8 + wave;
        for (int f = gw; f < M_TOT; f += NYQ_BLOCKS * 8) {
            const short* yr = (const short*)yb + (size_t)f * KROW;
            short8 v = *(const short8*)(yr + lane * 8);
            float sum = 0.f;
            #pragma unroll
            for (int u = 0; u < 8; ++u) {
                float e = __uint_as_float(((unsigned)(unsigned short)v[u]) << 16);
                sum += (u & 1) ? -e : e;
            }
            #pragma unroll
            for (int off = 32; off > 0; off >>= 1) sum += __shfl_xor(sum, off);
            if (lane == 0) {
                int b = f / T_FR, t = f - b * T_FR;
                float2 o; o.x = sum; o.y = 0.f;
                ((float2*)out)[((size_t)b * F_BINS + 1024) * T_FR + t] = o;
            }
        }
        return;
    }

    // block map: same-bm blocks land on 2 XCDs (A-panel L2 locality)
    const int bi = blockIdx.x;
    const int bm = (bi & 3) + ((bi >> 5) << 2);   // [0,108)
    const int bn = (bi >> 2) & 7;

    const int quad = lane >> 4, l15 = lane & 15;
    const int waveM = wave >> 2, waveN = wave & 3;

    // per-bn group params
    const int g1f   = bn >> 2;                    // 1 => K=1024 group
    const int Kg    = g1f ? 1024 : 512;
    const int NTt   = g1f ? 32 : 16;
    const int Koff  = (bn < 2) ? 0 : (bn < 4 ? 512 : 1024);
    const long bbase= g1f ? (long)WG02 + (long)(bn - 4) * 256 * 1024
                          : (long)bn * 256 * 512;
    const int kind  = (bn < 2) ? 0 : (bn < 4 ? 2 : 1);
    const int bnl   = (bn < 2) ? bn : (bn < 4 ? bn - 2 : bn - 4);

    // staging addressing
    const int l4 = lane >> 2, lc = lane & 3;
    const int swz = (lc ^ ((l4 >> 1) & 3)) * 8;
    int am = bm * 128 + wave * 16 + l4;
    if (am > M_TOT - 1) am = M_TOT - 1;           // clamp; masked at store
    const int aoff  = am * KROW + Koff + swz;
    const int brl   = wave * 32 + l4;
    const long boff0 = bbase + (long)brl * Kg + swz;
    const long boff1 = boff0 + (long)16 * Kg;
    const int adst = wave * 512;
    const int bdst = wave * 1024;

    // read addressing
    const int rchunk = (quad ^ ((l15 >> 1) & 3)) * 8;
    const int ara = (waveM * 64 + l15) * 32 + rchunk;
    const int bra = (waveN * 64 + l15) * 32 + rchunk;

#define STAGE(BUF, K0) { \
        glds16(yb + aoff  + (K0), &lds[(BUF) * 4096 + adst]); \
        glds16(w2 + boff0 + (K0), &lds[12288 + (BUF) * 8192 + bdst]); \
        glds16(w2 + boff1 + (K0), &lds[12288 + (BUF) * 8192 + bdst + 512]); }

    short8 xf[4], wf[4];
    floatx4 acc[4][4] = {};

    STAGE(0, 0);
    STAGE(1, 32);
    VMW(3);
    BARRIER;

    int r0 = 0, r1 = 1, r2 = 2;
    #pragma unroll 1
    for (int t = 0; t < NTt; ++t) {
        if (t < NTt - 2) STAGE(r2, (t + 2) * 32);
        if (t < NTt - 2)      { VMW(3); }
        else if (t == NTt - 2){ VMW(0); }
        SP1;
        wf[0] = *(const short8*)&lds[12288 + r0 * 8192 + bra];
        #pragma unroll
        for (int j = 0; j < 4; ++j)
            xf[j] = *(const short8*)&lds[r0 * 4096 + ara + j * 512];
        #pragma unroll
        for (int i = 1; i < 4; ++i)
            wf[i] = *(const short8*)&lds[12288 + r0 * 8192 + bra + i * 512];
        #pragma unroll
        for (int i = 0; i < 4; ++i)
            #pragma unroll
            for (int j = 0; j < 4; ++j)
                acc[i][j] = __builtin_amdgcn_mfma_f32_16x16x32_bf16(wf[i], xf[j], acc[i][j], 0, 0, 0);
        SP0;
        if (t < NTt - 1) BARRIER;
        int tmp = r0; r0 = r1; r1 = r2; r2 = tmp;
    }

    // epilogue: columns are (Re, Im) pairs; signs already folded into weights.
    float2* __restrict__ out2 = (float2*)out;
    #pragma unroll
    for (int j = 0; j < 4; ++j) {
        int m = bm * 128 + waveM * 64 + j * 16 + l15;
        if (m >= M_TOT) continue;
        int b = m / T_FR, t = m - b * T_FR;
        long tb = (long)b * (F_BINS * T_FR) + t;
        #pragma unroll
        for (int i = 0; i < 4; ++i) {
            #pragma unroll
            for (int p = 0; p < 2; ++p) {
                int pi = bnl * 128 + waveN * 32 + i * 8 + quad * 2 + p;  // pair idx in group
                int k = (kind == 0) ? 4 * pi
                      : (kind == 2) ? 4 * pi + 2
                      : (pi < 256 ? 4 * pi + 1 : 4 * pi - 1021);
                float2 v; v.x = acc[i][j][2 * p]; v.y = acc[i][j][2 * p + 1];
                out2[tb + (long)k * T_FR] = v;
            }
        }
    }
}

extern "C" void kernel_launch(void* const* d_in, const int* in_sizes, int n_in,
                              void* d_out, int out_size, void* d_ws, size_t ws_size,
                              hipStream_t stream) {
    const float* x    = (const float*)d_in[0];
    const float* wcos = (const float*)d_in[1];
    float* out = (float*)d_out;

    // ws: Y bf16 [13792][2048] (56.5 MB) then weights bf16 (3.1 MB) ~= 59.7 MB
    __hip_bfloat16* yb = (__hip_bfloat16*)d_ws;
    __hip_bfloat16* w2 = (__hip_bfloat16*)((char*)d_ws + (size_t)M_TOT * KROW * 2);

    k_prep<<<BF_BLOCKS + WGT_BLOCKS, 512, 0, stream>>>(x, wcos, yb, w2);
    k_gemm<<<GEMM_BLOCKS + NYQ_BLOCKS, 512, 0, stream>>>(yb, w2, out);
}

// Round 7
// 217.064 us; speedup vs baseline: 1.2638x; 1.0300x over previous
//
#include <hip/hip_runtime.h>
#include <hip/hip_bf16.h>

// ---- problem constants ----
#define L_IN   220500
#define BATCH  32
#define T_FR   431               // frames per batch
#define F_BINS 1025
#define M_TOT  (BATCH * T_FR)    // 13792 frames
#define KROW   2048              // Y row: Y0[512] | Y2[512] | Y1re[512] | Y1im[512]
// radix-4 factorization: X[4u+r] = sum_q Y_r[q] e^{-2pi i (4u+r) q / 2048}
//   Y0 = a0+a1+a2+a3 ; Y2 = a0-a1+a2-a3 ; Y1 = (a0-a2) + i(a3-a1),  a_p = win[512p+q]*x[.]
//   r=3 outputs via conjugate symmetry of r=1 ; k=1024 = sum Y0*(-1)^q (free).
// weights (pure trig, bf16): g0g2 = 1024 rows x 512 ; g1 = 1024 rows x 1024
#define WG02   524288
#define WG1    1048576
#define GEMM_BLOCKS 432          // paired jobs: 108 bm x 4 j; each block = K512 then K1024 tile
#define NYQ_BLOCKS  48
#define BF_BLOCKS   1728         // 54 per batch x 32, 8 frames/block
#define WGT_BLOCKS  384          // (WG02+WG1)/4096

typedef short short8 __attribute__((ext_vector_type(8)));
typedef float floatx4 __attribute__((ext_vector_type(4)));

__device__ __forceinline__ void glds16(const void* g, void* l) {
    __builtin_amdgcn_global_load_lds(
        (const __attribute__((address_space(1))) void*)g,
        (__attribute__((address_space(3))) void*)l, 16, 0, 0);
}

__device__ __forceinline__ short f2bf(float f) {
    __hip_bfloat16 h = __float2bfloat16(f);
    return *reinterpret_cast<short*>(&h);
}

// ---- pass 1: butterfly (blocks 0..1727) + trig weight gen (1728..2111) ----
__global__ __launch_bounds__(512) void k_prep(const float* __restrict__ x,
        const float* __restrict__ wcos,
        __hip_bfloat16* __restrict__ yb, __hip_bfloat16* __restrict__ w2) {
    const int blk = blockIdx.x, tid = threadIdx.x;
    if (blk < BF_BLOCKS) {
        int b = blk / 54, rem = blk - b * 54;
        int t = rem * 8 + (tid >> 6);
        if (t >= T_FR) return;
        int q = (tid & 63) * 8;
        const float* xb = x + (size_t)b * L_IN;
        float a[4][8];
        #pragma unroll
        for (int p = 0; p < 4; ++p) {
            // window = wcos row 0 (win[s]*cos(0))
            const float4* wv = (const float4*)(wcos + 512 * p + q);
            float4 w0 = wv[0], w1 = wv[1];
            float w[8] = {w0.x,w0.y,w0.z,w0.w,w1.x,w1.y,w1.z,w1.w};
            int jb = t * 512 + 512 * p + q - 1024;     // reflect-padded origin
            if (jb >= 0 && jb <= L_IN - 8) {
                const float4* s4 = (const float4*)(xb + jb);
                float4 v0 = s4[0], v1 = s4[1];
                float v[8] = {v0.x,v0.y,v0.z,v0.w,v1.x,v1.y,v1.z,v1.w};
                #pragma unroll
                for (int u = 0; u < 8; ++u) a[p][u] = v[u] * w[u];
            } else {
                #pragma unroll
                for (int u = 0; u < 8; ++u) {
                    int j = jb + u;
                    if (j < 0) j = -j;
                    if (j >= L_IN) j = 2 * L_IN - 2 - j;
                    a[p][u] = xb[j] * w[u];
                }
            }
        }
        short8 y0, y2, yre, yim;
        #pragma unroll
        for (int u = 0; u < 8; ++u) {
            y0[u]  = f2bf(a[0][u] + a[1][u] + a[2][u] + a[3][u]);
            y2[u]  = f2bf(a[0][u] - a[1][u] + a[2][u] - a[3][u]);
            yre[u] = f2bf(a[0][u] - a[2][u]);
            yim[u] = f2bf(a[3][u] - a[1][u]);
        }
        short* yr = (short*)yb + (size_t)(b * T_FR + t) * KROW;
        *(short8*)(yr + q)        = y0;
        *(short8*)(yr + 512 + q)  = y2;
        *(short8*)(yr + 1024 + q) = yre;
        *(short8*)(yr + 1536 + q) = yim;
    } else {
        // weights; columns come in (Re, Im) pairs, signs folded so epilogue stores raw.
        long e0 = (long)(blk - BF_BLOCKS) * 4096 + (long)tid * 8;
        short8 o;
        const float SC = 3.0679615757712823e-3f;   // 2*pi/2048
        if (e0 < WG02) {           // g0 (rows 0..511, k=4u) / g2 (rows 512..1023, k=4u+2)
            int n = (int)(e0 >> 9), q0 = (int)(e0 & 511);
            int c = n & 1;
            int k = (n < 512) ? 4 * (n >> 1) : 4 * ((n - 512) >> 1) + 2;
            #pragma unroll
            for (int u = 0; u < 8; ++u) {
                int ph = (k * (q0 + u)) & 2047;
                float s, cc;
                __sincosf((float)ph * SC, &s, &cc);
                o[u] = f2bf(c ? -s : cc);          // ReX = sum Y cos ; ImX = -sum Y sin
            }
        } else {                   // g1: rows n=2v+c, K=1024 over (Yre[512] ++ Yim[512])
            long f = e0 - WG02;
            int n = (int)(f >> 10), q0 = (int)(f & 1023);
            int c = n & 1, v = n >> 1;
            int half = q0 >> 9, qq = q0 & 511;
            int k = (v < 256) ? 4 * v + 1 : 3069 - 4 * v;   // v>=256: conj mirror
            #pragma unroll
            for (int u = 0; u < 8; ++u) {
                int ph = (k * (qq + u)) & 2047;
                float s, cc;
                __sincosf((float)ph * SC, &s, &cc);
                float val;
                if (v < 256) val = c ? (half ? cc : -s) : (half ? s : cc);
                else         val = c ? (half ? -cc : s) : (half ? s : cc); // conj branch
                o[u] = f2bf(val);
            }
        }
        *(short8*)((short*)w2 + e0) = o;
    }
}

// ---- pass 2: factored GEMM, PAIRED JOBS: each block runs a K=512 tile (g0/g2)
// then the K=1024 tile (g1) at the same bm -> 432 uniform 48-iter blocks + 48 nyq
// = 480 blocks <= 512 residency slots: ONE dispatch round, no ragged tail.
// Machinery unchanged from verified round: BM=128/BN=256, BK=32, triple-buffered
// LDS, (row>>1)&3 chunk swizzle (0 conflicts measured), counted vmcnt(3) placed
// LATE (after MFMA) so staging loads get ~2 iterations of latency budget.
#define BARRIER { asm volatile("" ::: "memory"); __builtin_amdgcn_s_barrier(); asm volatile("" ::: "memory"); }
#define VMW(N)  asm volatile("s_waitcnt vmcnt(" #N ")" ::: "memory")
#define SP1     __builtin_amdgcn_s_setprio(1)
#define SP0     __builtin_amdgcn_s_setprio(0)

__global__ __launch_bounds__(512, 2) void k_gemm(
    const __hip_bfloat16* __restrict__ yb,
    const __hip_bfloat16* __restrict__ w2,
    float* __restrict__ out) {

    __shared__ short lds[36864];   // 72 KiB
    const int tid = threadIdx.x, wave = tid >> 6, lane = tid & 63;

    // ---- Nyquist tail blocks: k=1024 = sum_q Y0[q]*(-1)^q ----
    if (blockIdx.x >= GEMM_BLOCKS) {
        const int gw = (blockIdx.x - GEMM_BLOCKS) * 8 + wave;
        for (int f = gw; f < M_TOT; f += NYQ_BLOCKS * 8) {
            const short* yr = (const short*)yb + (size_t)f * KROW;
            short8 v = *(const short8*)(yr + lane * 8);
            float sum = 0.f;
            #pragma unroll
            for (int u = 0; u < 8; ++u) {
                float e = __uint_as_float(((unsigned)(unsigned short)v[u]) << 16);
                sum += (u & 1) ? -e : e;
            }
            #pragma unroll
            for (int off = 32; off > 0; off >>= 1) sum += __shfl_xor(sum, off);
            if (lane == 0) {
                int b = f / T_FR, t = f - b * T_FR;
                float2 o; o.x = sum; o.y = 0.f;
                ((float2*)out)[((size_t)b * F_BINS + 1024) * T_FR + t] = o;
            }
        }
        return;
    }

    // block map: bm = (bi&3) + 4*(bi>>4), j = (bi>>2)&3  (same-bm blocks cluster on XCDs)
    const int bi = blockIdx.x;
    const int j  = (bi >> 2) & 3;
    const int bm = (bi & 3) + ((bi >> 4) << 2);   // [0,108)

    const int quad = lane >> 4, l15 = lane & 15;
    const int waveM = wave >> 2, waveN = wave & 3;

    // job-invariant addressing
    const int l4 = lane >> 2, lc = lane & 3;
    const int swz = (lc ^ ((l4 >> 1) & 3)) * 8;
    int am = bm * 128 + wave * 16 + l4;
    if (am > M_TOT - 1) am = M_TOT - 1;           // clamp; masked at store
    const int abase = am * KROW;
    const int brl   = wave * 32 + l4;
    const int adst  = wave * 512;
    const int bdst  = wave * 1024;
    const int rchunk = (quad ^ ((l15 >> 1) & 3)) * 8;
    const int ara = (waveM * 64 + l15) * 32 + rchunk;
    const int bra = (waveN * 64 + l15) * 32 + rchunk;

    float2* __restrict__ out2 = (float2*)out;

#define STAGE(BUF, K0) { \
        glds16(yb + aoff  + (K0), &lds[(BUF) * 4096 + adst]); \
        glds16(w2 + boff0 + (K0), &lds[12288 + (BUF) * 8192 + bdst]); \
        glds16(w2 + boff1 + (K0), &lds[12288 + (BUF) * 8192 + bdst + 512]); }

    #pragma unroll 1
    for (int jj = 0; jj < 2; ++jj) {
        // per-job params: jj=0 -> g0/g2 (K=512), jj=1 -> g1 (K=1024)
        const int Kg   = jj ? 1024 : 512;
        const int NTt  = jj ? 32 : 16;
        const int kind = jj ? 1 : (j < 2 ? 0 : 2);
        const int Koff = jj ? 1024 : (j < 2 ? 0 : 512);
        const long bbase = jj ? (long)WG02 + (long)j * 256 * 1024
                              : (long)j * 256 * 512;
        const int bnl = jj ? j : (j & 1);

        const int  aoff  = abase + Koff + swz;
        const long boff0 = bbase + (long)brl * Kg + swz;
        const long boff1 = boff0 + (long)(16 * Kg);

        short8 xf[4], wf[4];
        floatx4 acc[4][4] = {};

        if (jj) BARRIER;       // prior job's last ds_reads retired (consumed by its MFMAs)
        STAGE(0, 0);
        STAGE(1, 32);
        VMW(3);                // vmcnt retires in issue order: older epilogue stores drain too
        BARRIER;

        int r0 = 0, r1 = 1, r2 = 2;
        #pragma unroll 1
        for (int t = 0; t < NTt; ++t) {
            if (t < NTt - 2) STAGE(r2, (t + 2) * 32);
            // reads ordered to feed the MFMA ladder just-in-time
            wf[0] = *(const short8*)&lds[12288 + r0 * 8192 + bra];
            #pragma unroll
            for (int jm = 0; jm < 4; ++jm)
                xf[jm] = *(const short8*)&lds[r0 * 4096 + ara + jm * 512];
            #pragma unroll
            for (int i = 1; i < 4; ++i)
                wf[i] = *(const short8*)&lds[12288 + r0 * 8192 + bra + i * 512];
            SP1;
            #pragma unroll
            for (int i = 0; i < 4; ++i)
                #pragma unroll
                for (int jm = 0; jm < 4; ++jm)
                    acc[i][jm] = __builtin_amdgcn_mfma_f32_16x16x32_bf16(wf[i], xf[jm], acc[i][jm], 0, 0, 0);
            SP0;
            if (t < NTt - 1) {
                if (t < NTt - 2) { VMW(3); } else { VMW(0); }
                BARRIER;
            }
            int tmp = r0; r0 = r1; r1 = r2; r2 = tmp;
        }

        // epilogue: columns are (Re, Im) pairs; signs already folded into weights.
        #pragma unroll
        for (int jm = 0; jm < 4; ++jm) {
            int m = bm * 128 + waveM * 64 + jm * 16 + l15;
            if (m >= M_TOT) continue;
            int b = m / T_FR, t = m - b * T_FR;
            long tb = (long)b * (F_BINS * T_FR) + t;
            #pragma unroll
            for (int i = 0; i < 4; ++i) {
                #pragma unroll
                for (int p = 0; p < 2; ++p) {
                    int pi = bnl * 128 + waveN * 32 + i * 8 + quad * 2 + p;
                    int k = (kind == 0) ? 4 * pi
                          : (kind == 2) ? 4 * pi + 2
                          : (pi < 256 ? 4 * pi + 1 : 4 * pi - 1021);
                    float2 v; v.x = acc[i][jm][2 * p]; v.y = acc[i][jm][2 * p + 1];
                    out2[tb + (long)k * T_FR] = v;
                }
            }
        }
    }
}

extern "C" void kernel_launch(void* const* d_in, const int* in_sizes, int n_in,
                              void* d_out, int out_size, void* d_ws, size_t ws_size,
                              hipStream_t stream) {
    const float* x    = (const float*)d_in[0];
    const float* wcos = (const float*)d_in[1];
    float* out = (float*)d_out;

    // ws: Y bf16 [13792][2048] (56.5 MB) then weights bf16 (3.1 MB) ~= 59.7 MB
    __hip_bfloat16* yb = (__hip_bfloat16*)d_ws;
    __hip_bfloat16* w2 = (__hip_bfloat16*)((char*)d_ws + (size_t)M_TOT * KROW * 2);

    k_prep<<<BF_BLOCKS + WGT_BLOCKS, 512, 0, stream>>>(x, wcos, yb, w2);
    k_gemm<<<GEMM_BLOCKS + NYQ_BLOCKS, 512, 0, stream>>>(yb, w2, out);
}